// Round 6
// baseline (1037.924 us; speedup 1.0000x reference)
//
#include <hip/hip_runtime.h>

#define N_NODES 100000
#define N_EDGES 3200000
#define D_IN    512
#define D_OUT   256

// bucket binning params
#define NB        1563            // ceil(100000 / 64) buckets of 64 nodes
#define NBLK_BIN  128
#define T_BIN     ((N_EDGES + NBLK_BIN - 1) / NBLK_BIN)   // 25000

typedef short sh8 __attribute__((ext_vector_type(8)));
typedef float f4  __attribute__((ext_vector_type(4)));

__device__ __forceinline__ unsigned short bf16rn(float f) {
    unsigned u = __float_as_uint(f);
    unsigned r = (u + 0x7FFFu + ((u >> 16) & 1u)) >> 16;
    return (unsigned short)r;
}

__device__ __forceinline__ float bf2f(unsigned short h) {
    return __uint_as_float((unsigned)h << 16);
}

__device__ __forceinline__ void gload_lds16(const void* g, void* l) {
    __builtin_amdgcn_global_load_lds(
        (const __attribute__((address_space(1))) void*)g,
        (__attribute__((address_space(3))) void*)l, 16, 0, 0);
}

// ---------------------------------------------------------------------------
// Pack W[512][256] fp32 -> bf16 hi/lo in MFMA-fragment-major order
// ---------------------------------------------------------------------------
__global__ __launch_bounds__(256) void wpack_kernel(const float* __restrict__ w,
                                                    short* __restrict__ wp) {
    const int id = blockIdx.x * 256 + threadIdx.x;   // 0..16383
    const int l = id & 63;
    const int b = (id >> 6) & 15;
    const int s = id >> 10;
    const int n  = b * 16 + (l & 15);
    const int k0 = s * 32 + (l >> 4) * 8;
    sh8 hi8, lo8;
#pragma unroll
    for (int j = 0; j < 8; ++j) {
        float f = w[(size_t)(k0 + j) * D_OUT + n];
        unsigned short h = bf16rn(f);
        float fh = bf2f(h);
        hi8[j] = (short)h;
        lo8[j] = (short)bf16rn(f - fh);
    }
    short* dst = wp + (size_t)(s * 16 + b) * 1024 + (size_t)l * 8;
    *reinterpret_cast<sh8*>(dst)       = hi8;
    *reinterpret_cast<sh8*>(dst + 512) = lo8;
}

// ---------------------------------------------------------------------------
// GEMM: xw_bf16[N,256] = x[N,512] @ W — split-bf16 MFMA (hi*hi + hi*lo + lo*hi)
// ---------------------------------------------------------------------------
__global__ __launch_bounds__(256) void gemm_mfma(const float* __restrict__ x,
                                                 const short* __restrict__ wp,
                                                 unsigned short* __restrict__ xwh) {
    __shared__ __align__(16) short A_lds[64 * 64];
    __shared__ __align__(16) short B_lds[16384];

    const int tid  = threadIdx.x;
    const int wave = tid >> 6;
    const int lane = tid & 63;
    const int r0   = blockIdx.x * 64;

    f4 acc[4][4];
#pragma unroll
    for (int i = 0; i < 4; ++i)
#pragma unroll
        for (int j = 0; j < 4; ++j) acc[i][j] = (f4){0.f, 0.f, 0.f, 0.f};

    const int sr  = tid >> 2;
    const int skg = tid & 3;
    const int grow = r0 + sr;
    const bool rok = grow < N_NODES;
    const float* xbase = x + (size_t)grow * D_IN + skg * 8;
    const int aw_hi = sr * 128 + ((skg ^ (sr & 7)) << 4);
    const int aw_lo = aw_hi ^ 0x40;
    char* Ac = reinterpret_cast<char*>(A_lds);
    char* Bc = reinterpret_cast<char*>(B_lds);

    const int kg  = lane >> 4;
    const int l7  = lane & 7;
    const int l15 = lane & 15;

    for (int s = 0; s < 16; ++s) {
        const short* bs = wp + (size_t)s * 16384;
#pragma unroll
        for (int rr = 0; rr < 8; ++rr) {
            gload_lds16(bs + rr * 2048 + tid * 8, &B_lds[rr * 2048 + wave * 512]);
        }
        float fv[8] = {0.f, 0.f, 0.f, 0.f, 0.f, 0.f, 0.f, 0.f};
        if (rok) {
            float4 v0 = *reinterpret_cast<const float4*>(xbase + s * 32);
            float4 v1 = *reinterpret_cast<const float4*>(xbase + s * 32 + 4);
            fv[0] = v0.x; fv[1] = v0.y; fv[2] = v0.z; fv[3] = v0.w;
            fv[4] = v1.x; fv[5] = v1.y; fv[6] = v1.z; fv[7] = v1.w;
        }
        sh8 hi8, lo8;
#pragma unroll
        for (int j = 0; j < 8; ++j) {
            unsigned short h = bf16rn(fv[j]);
            float fh = bf2f(h);
            hi8[j] = (short)h;
            lo8[j] = (short)bf16rn(fv[j] - fh);
        }
        *reinterpret_cast<sh8*>(Ac + aw_hi) = hi8;
        *reinterpret_cast<sh8*>(Ac + aw_lo) = lo8;
        __syncthreads();

        sh8 ah[4], al[4], bh[4], bl[4];
#pragma unroll
        for (int mf = 0; mf < 4; ++mf) {
            const int rowb = (mf * 16 + l15) * 128;
            const int ghi  = (kg ^ l7) << 4;
            ah[mf] = *reinterpret_cast<const sh8*>(Ac + rowb + ghi);
            al[mf] = *reinterpret_cast<const sh8*>(Ac + rowb + (ghi ^ 0x40));
        }
#pragma unroll
        for (int nf = 0; nf < 4; ++nf) {
            const int base = (wave * 4 + nf) * 2048 + lane * 16;
            bh[nf] = *reinterpret_cast<const sh8*>(Bc + base);
            bl[nf] = *reinterpret_cast<const sh8*>(Bc + base + 1024);
        }
#pragma unroll
        for (int mf = 0; mf < 4; ++mf)
#pragma unroll
            for (int nf = 0; nf < 4; ++nf) {
                acc[mf][nf] = __builtin_amdgcn_mfma_f32_16x16x32_bf16(ah[mf], bh[nf], acc[mf][nf], 0, 0, 0);
                acc[mf][nf] = __builtin_amdgcn_mfma_f32_16x16x32_bf16(ah[mf], bl[nf], acc[mf][nf], 0, 0, 0);
                acc[mf][nf] = __builtin_amdgcn_mfma_f32_16x16x32_bf16(al[mf], bh[nf], acc[mf][nf], 0, 0, 0);
            }
        __syncthreads();
    }

    const int orow = (lane >> 4) * 4;
    const int ocol = wave * 64 + l15;
#pragma unroll
    for (int mf = 0; mf < 4; ++mf) {
#pragma unroll
        for (int rg = 0; rg < 4; ++rg) {
            const int row = r0 + mf * 16 + orow + rg;
            if (row < N_NODES) {
                unsigned short* dst = xwh + (size_t)row * D_OUT + ocol;
#pragma unroll
                for (int nf = 0; nf < 4; ++nf) dst[nf * 16] = bf16rn(acc[mf][nf][rg]);
            }
        }
    }
}

// ---------------------------------------------------------------------------
// Per-node degree histogram + scan (rowptr / pos) — unchanged
// ---------------------------------------------------------------------------
__global__ void zero_deg_kernel(int* __restrict__ deg) {
    int i = blockIdx.x * blockDim.x + threadIdx.x;
    if (i < N_NODES) deg[i] = 0;
}

__global__ void hist_kernel(const int* __restrict__ erow, int* __restrict__ deg) {
    for (int e = blockIdx.x * blockDim.x + threadIdx.x; e < N_EDGES;
         e += gridDim.x * blockDim.x) {
        atomicAdd(&deg[erow[e]], 1);
    }
}

#define SCAN_CHUNK 1024

__global__ __launch_bounds__(256) void scan_part_kernel(const int* __restrict__ deg,
                                                        int* __restrict__ inc,
                                                        int* __restrict__ chunkSums) {
    __shared__ int lds[256];
    const int tid = threadIdx.x;
    const int idx = blockIdx.x * SCAN_CHUNK + tid * 4;
    int v0 = (idx + 0 < N_NODES) ? deg[idx + 0] : 0;
    int v1 = (idx + 1 < N_NODES) ? deg[idx + 1] : 0;
    int v2 = (idx + 2 < N_NODES) ? deg[idx + 2] : 0;
    int v3 = (idx + 3 < N_NODES) ? deg[idx + 3] : 0;
    v1 += v0; v2 += v1; v3 += v2;
    lds[tid] = v3;
    __syncthreads();
    for (int off = 1; off < 256; off <<= 1) {
        int t = (tid >= off) ? lds[tid - off] : 0;
        __syncthreads();
        lds[tid] += t;
        __syncthreads();
    }
    const int texc = (tid > 0) ? lds[tid - 1] : 0;
    if (idx + 0 < N_NODES) inc[idx + 0] = v0 + texc;
    if (idx + 1 < N_NODES) inc[idx + 1] = v1 + texc;
    if (idx + 2 < N_NODES) inc[idx + 2] = v2 + texc;
    if (idx + 3 < N_NODES) inc[idx + 3] = v3 + texc;
    if (tid == 255) chunkSums[blockIdx.x] = lds[255];
}

__global__ __launch_bounds__(128) void scan_chunks_kernel(const int* __restrict__ chunkSums,
                                                          int* __restrict__ chunkOffs,
                                                          int nChunks) {
    __shared__ int lds[128];
    const int tid = threadIdx.x;
    lds[tid] = (tid < nChunks) ? chunkSums[tid] : 0;
    __syncthreads();
    for (int off = 1; off < 128; off <<= 1) {
        int t = (tid >= off) ? lds[tid - off] : 0;
        __syncthreads();
        lds[tid] += t;
        __syncthreads();
    }
    if (tid < nChunks) chunkOffs[tid] = (tid > 0) ? lds[tid - 1] : 0;
}

__global__ void scan_final_kernel(const int* __restrict__ inc,
                                  const int* __restrict__ chunkOffs,
                                  int* __restrict__ rowptr,
                                  int* __restrict__ pos) {
    int i = blockIdx.x * blockDim.x + threadIdx.x;
    if (i < N_NODES) {
        int val = inc[i] + chunkOffs[i / SCAN_CHUNK];
        rowptr[i + 1] = val;
        if (i + 1 < N_NODES) pos[i + 1] = val;
        if (i == 0) { rowptr[0] = 0; pos[0] = 0; }
    }
}

// ---------------------------------------------------------------------------
// Bucket binning: 1563 buckets of 64 nodes.  Replaces the random fill scatter.
// K1: per-block bucket histograms
// ---------------------------------------------------------------------------
__global__ __launch_bounds__(256) void bucket_count_kernel(const int* __restrict__ erow,
                                                           int* __restrict__ blockHist) {
    __shared__ int h[NB];
    for (int i = threadIdx.x; i < NB; i += 256) h[i] = 0;
    __syncthreads();
    const int start = blockIdx.x * T_BIN;
    const int stop  = min(start + T_BIN, N_EDGES);
    for (int e = start + threadIdx.x; e < stop; e += 256)
        atomicAdd(&h[erow[e] >> 6], 1);
    __syncthreads();
    int* dst = blockHist + (size_t)blockIdx.x * NB;
    for (int i = threadIdx.x; i < NB; i += 256) dst[i] = h[i];
}

// K2 (1 block): column-scan blockHist -> per-(block,bucket) bases; bucket scan -> bptr
__global__ __launch_bounds__(256) void bucket_scan_kernel(int* __restrict__ blockHist,
                                                          int* __restrict__ bptr) {
    __shared__ int tot[NB];
    __shared__ int lds[256];
    const int tid = threadIdx.x;
    // phase 1: per-bucket totals + per-block exclusive prefix (in place)
    for (int b = tid; b < NB; b += 256) {
        int run = 0;
        for (int blk = 0; blk < NBLK_BIN; ++blk) {
            int v = blockHist[(size_t)blk * NB + b];
            blockHist[(size_t)blk * NB + b] = run;
            run += v;
        }
        tot[b] = run;
    }
    __syncthreads();
    // phase 2: exclusive scan over buckets (chunked)
    int carry = 0;
    for (int c = 0; c < (NB + 255) / 256; ++c) {
        const int idx = c * 256 + tid;
        const int v = (idx < NB) ? tot[idx] : 0;
        lds[tid] = v;
        __syncthreads();
        for (int off = 1; off < 256; off <<= 1) {
            int t = (tid >= off) ? lds[tid - off] : 0;
            __syncthreads();
            lds[tid] += t;
            __syncthreads();
        }
        const int exc = carry + lds[tid] - v;
        if (idx < NB) { tot[idx] = exc; bptr[idx] = exc; }
        if (idx == NB - 1) bptr[NB] = exc + v;
        carry += lds[255];
        __syncthreads();
    }
    // phase 3: bases += bucket offset
    for (int b = tid; b < NB; b += 256) {
        const int off = tot[b];
        for (int blk = 0; blk < NBLK_BIN; ++blk)
            blockHist[(size_t)blk * NB + b] += off;
    }
}

// K3: locality-friendly binned scatter. tpack = { (lrow<<17)|col , f32 val }
__global__ __launch_bounds__(256) void bucket_scatter_kernel(const int* __restrict__ erow,
                                                             const int* __restrict__ ecol,
                                                             const float* __restrict__ eval_,
                                                             const int* __restrict__ base,
                                                             int2* __restrict__ tpack) {
    __shared__ int lcnt[NB];
    for (int i = threadIdx.x; i < NB; i += 256) lcnt[i] = 0;
    __syncthreads();
    const int start = blockIdx.x * T_BIN;
    const int stop  = min(start + T_BIN, N_EDGES);
    const int* bbase = base + (size_t)blockIdx.x * NB;
    for (int e = start + threadIdx.x; e < stop; e += 256) {
        const int r = erow[e];
        const int b = r >> 6;
        const int loc = atomicAdd(&lcnt[b], 1);
        const int p = bbase[b] + loc;
        int2 pk;
        pk.x = ((r & 63) << 17) | ecol[e];
        pk.y = __float_as_int(eval_[e]);
        tpack[p] = pk;
    }
}

// K4: within-bucket node fill — pos atomics hit 64 counters, writes land in a
// ~16KB contiguous window (L2-resident).  cpack = (col, val) per final slot.
__global__ __launch_bounds__(256) void bucket_fill_kernel(const int* __restrict__ bptr,
                                                          const int2* __restrict__ tpack,
                                                          int* __restrict__ pos,
                                                          int2* __restrict__ cpack) {
    const int b = blockIdx.x;
    const int beg = bptr[b], end = bptr[b + 1];
    const int rbase = b << 6;
    for (int e = beg + threadIdx.x; e < end; e += 256) {
        const int2 u = tpack[e];
        const int row = rbase + (u.x >> 17);
        const int p = atomicAdd(&pos[row], 1);
        int2 pk;
        pk.x = u.x & 0x1FFFF;
        pk.y = u.y;
        cpack[p] = pk;
    }
}

// ---------------------------------------------------------------------------
// Aggregate: one wave per node; lane = 4 consecutive bf16 cols (8B gather)
// ---------------------------------------------------------------------------
__global__ __launch_bounds__(256) void aggregate_kernel(const int* __restrict__ rowptr,
                                                        const int2* __restrict__ cpack,
                                                        const ushort4* __restrict__ xwh4,
                                                        const float* __restrict__ bias,
                                                        float* __restrict__ out) {
    const int gid  = blockIdx.x * blockDim.x + threadIdx.x;
    const int nid  = gid >> 6;
    const int lane = gid & 63;
    if (nid >= N_NODES) return;

    const int beg = rowptr[nid];
    const int end = rowptr[nid + 1];

    float4 acc = {0.f, 0.f, 0.f, 0.f};
    int e = beg;
    for (; e + 8 <= end; e += 8) {
        int2 p[8];
        ushort4 m[8];
#pragma unroll
        for (int j = 0; j < 8; ++j) p[j] = cpack[e + j];
#pragma unroll
        for (int j = 0; j < 8; ++j) m[j] = xwh4[(size_t)p[j].x * 64 + lane];
#pragma unroll
        for (int j = 0; j < 8; ++j) {
            const float v = __int_as_float(p[j].y);
            acc.x = fmaf(v, bf2f(m[j].x), acc.x);
            acc.y = fmaf(v, bf2f(m[j].y), acc.y);
            acc.z = fmaf(v, bf2f(m[j].z), acc.z);
            acc.w = fmaf(v, bf2f(m[j].w), acc.w);
        }
    }
    for (; e < end; ++e) {
        const int2 p = cpack[e];
        const float v = __int_as_float(p.y);
        const ushort4 m = xwh4[(size_t)p.x * 64 + lane];
        acc.x = fmaf(v, bf2f(m.x), acc.x);
        acc.y = fmaf(v, bf2f(m.y), acc.y);
        acc.z = fmaf(v, bf2f(m.z), acc.z);
        acc.w = fmaf(v, bf2f(m.w), acc.w);
    }

    const float4 b = reinterpret_cast<const float4*>(bias)[lane];
    float4 r;
    r.x = fmaxf(acc.x + b.x, 0.f);
    r.y = fmaxf(acc.y + b.y, 0.f);
    r.z = fmaxf(acc.z + b.z, 0.f);
    r.w = fmaxf(acc.w + b.w, 0.f);
    reinterpret_cast<float4*>(out)[(size_t)nid * 64 + lane] = r;
}

// ---------------------------------------------------------------------------
extern "C" void kernel_launch(void* const* d_in, const int* in_sizes, int n_in,
                              void* d_out, int out_size, void* d_ws, size_t ws_size,
                              hipStream_t stream) {
    const float* x     = (const float*)d_in[0];
    const int*   erow  = (const int*)d_in[1];
    const int*   ecol  = (const int*)d_in[2];
    const float* eval_ = (const float*)d_in[3];
    const float* w     = (const float*)d_in[4];
    const float* bias  = (const float*)d_in[5];
    float* out = (float*)d_out;

    char* ws = (char*)d_ws;
    size_t o = 0;
    unsigned short* xwh = (unsigned short*)(ws + o); o += (size_t)N_NODES * D_OUT * 2;  // 51.2 MB
    short* wp      = (short*)(ws + o); o += (size_t)16 * 16384 * 2;                     // 512 KB
    int*   rowptr  = (int*)(ws + o);   o += (((size_t)(N_NODES + 1) * 4) + 15) & ~(size_t)15;
    int*   pos     = (int*)(ws + o);   o += (size_t)N_NODES * 4;
    int*   deg     = (int*)(ws + o);   o += (size_t)N_NODES * 4;
    int*   inc     = (int*)(ws + o);   o += (size_t)N_NODES * 4;
    int*   chunkS  = (int*)(ws + o);   o += 1024;
    int*   chunkO  = (int*)(ws + o);   o += 1024;
    int*   bHist   = (int*)(ws + o);   o += (size_t)NBLK_BIN * NB * 4;                  // 800 KB
    int*   bptr    = (int*)(ws + o);   o += (((size_t)(NB + 1) * 4) + 15) & ~(size_t)15;
    int2*  tpack   = (int2*)(ws + o);  o += (size_t)N_EDGES * 8;                        // 25.6 MB
    int2*  cpack   = (int2*)(ws + o);  o += (size_t)N_EDGES * 8;                        // 25.6 MB

    const int nChunks = (N_NODES + SCAN_CHUNK - 1) / SCAN_CHUNK;   // 98

    // W pack + GEMM
    wpack_kernel<<<64, 256, 0, stream>>>(w, wp);
    gemm_mfma<<<(N_NODES + 63) / 64, 256, 0, stream>>>(x, wp, xwh);

    // per-node degree -> rowptr / pos
    zero_deg_kernel<<<(N_NODES + 255) / 256, 256, 0, stream>>>(deg);
    hist_kernel<<<2048, 256, 0, stream>>>(erow, deg);
    scan_part_kernel<<<nChunks, 256, 0, stream>>>(deg, inc, chunkS);
    scan_chunks_kernel<<<1, 128, 0, stream>>>(chunkS, chunkO, nChunks);
    scan_final_kernel<<<(N_NODES + 255) / 256, 256, 0, stream>>>(inc, chunkO, rowptr, pos);

    // two-level CSR build
    bucket_count_kernel<<<NBLK_BIN, 256, 0, stream>>>(erow, bHist);
    bucket_scan_kernel<<<1, 256, 0, stream>>>(bHist, bptr);
    bucket_scatter_kernel<<<NBLK_BIN, 256, 0, stream>>>(erow, ecol, eval_, bHist, tpack);
    bucket_fill_kernel<<<NB, 256, 0, stream>>>(bptr, tpack, pos, cpack);

    // Aggregate + bias + relu
    aggregate_kernel<<<(N_NODES * 64) / 256, 256, 0, stream>>>(
        rowptr, cpack, reinterpret_cast<const ushort4*>(xwh), bias, out);
}